// Round 5
// baseline (267.668 us; speedup 1.0000x reference)
//
#include <hip/hip_runtime.h>
#include <stdint.h>

typedef float v4f __attribute__((ext_vector_type(4)));
typedef short v8s __attribute__((ext_vector_type(8)));

#define SZ_BHTD 8388608   // B*H*T*DH
#define SZ_HTD  131072    // T*DH

#define GL2LDS(g, l) __builtin_amdgcn_global_load_lds( \
    (const __attribute__((address_space(1))) void*)(g), \
    (__attribute__((address_space(3))) void*)(l), 16, 0, 0)

#define MFMA(a, b, c) __builtin_amdgcn_mfma_f32_16x16x32_bf16(a, b, c, 0, 0, 0)

__device__ __forceinline__ uint16_t f2bf(float f){
  uint32_t u = __float_as_uint(f);
  u += 0x7fffu + ((u >> 16) & 1u);
  return (uint16_t)(u >> 16);
}
__device__ __forceinline__ float bf2f(uint16_t v){
  return __uint_as_float(((uint32_t)v) << 16);
}

// Fused conversions: [0,8192): x fp32->bf16; [8192,8960): W transpose->bf16; [8960,8976): pkv^T bf16
__global__ __launch_bounds__(256) void k_conv(const float* __restrict__ x,
                                              const float* __restrict__ Wq, const float* __restrict__ Wk,
                                              const float* __restrict__ Wv, const float* __restrict__ pkv,
                                              uint16_t* __restrict__ xb, uint16_t* __restrict__ wt,
                                              uint16_t* __restrict__ pkvT){
  if (blockIdx.x < 8192){
    int i = blockIdx.x*256 + threadIdx.x;
    const float4 v = ((const float4*)x)[i];
    ushort4 o; o.x = f2bf(v.x); o.y = f2bf(v.y); o.z = f2bf(v.z); o.w = f2bf(v.w);
    ((ushort4*)xb)[i] = o;
    return;
  }
  __shared__ float t[64][65];
  if (blockIdx.x >= 8960){
    const int h = blockIdx.x - 8960;
    for (int idx = threadIdx.x; idx < 4096; idx += 256)
      t[idx >> 6][idx & 63] = pkv[h*4096 + idx];          // t[d][e]
    __syncthreads();
    for (int idx = threadIdx.x; idx < 4096; idx += 256){
      int e = idx >> 6, d = idx & 63;
      pkvT[h*4096 + idx] = f2bf(t[d][e]);                 // pkvT[h][e][d]
    }
    return;
  }
  const int blk2 = blockIdx.x - 8192;          // [0,768)
  const int z = blk2 >> 8, y = (blk2 >> 4) & 15, xx = blk2 & 15;
  const float* W = z==0 ? Wq : (z==1 ? Wk : Wv);
  int n0 = xx*64, k0 = y*64;
  for (int idx = threadIdx.x; idx < 4096; idx += 256){
    int r = idx >> 6, c = idx & 63;
    t[r][c] = W[(k0+r)*1024 + n0 + c];
  }
  __syncthreads();
  for (int idx = threadIdx.x; idx < 4096; idx += 256){
    int r = idx >> 6, c = idx & 63;   // r: local n, c: local k
    wt[(size_t)(z*1024 + n0 + r)*1024 + k0 + c] = f2bf(t[c][r]);
  }
}

// QKV GEMM, 128x128 tile, BK=64, global_load_lds + XOR swizzle (conflict-free, verified R4).
// Epilogue emits: Q row-major (slot0), K row-major (slot1), K^T per-chunk (KTg), V^T per-chunk (slot2).
__global__ __launch_bounds__(256) void k_gemm(const uint16_t* __restrict__ Xb, const uint16_t* __restrict__ Wt,
                                              uint16_t* __restrict__ qkv, uint16_t* __restrict__ KTg){
  __shared__ uint16_t As[128*64];
  __shared__ uint16_t Bs[128*64];
  const int tid = threadIdx.x;
  const int lane = tid & 63, w = tid >> 6;
  const int quad = lane >> 4, l16 = lane & 15;
  const int wm = (w >> 1)*64, wn = (w & 1)*64;
  const int bm = blockIdx.x, bn = blockIdx.y;
  v4f acc[4][4] = {};
  const uint16_t* Ag = Xb + (size_t)(bm*128)*1024;
  const uint16_t* Bg = Wt + (size_t)(bn*128)*1024;
  const int rA = lane >> 3;                     // row within 8-row chunk
  const int ce = (((lane & 7) ^ rA) * 8);       // swizzled 16B column chunk
  const int xr = l16 & 7;                       // reader-side XOR key
  for (int k0 = 0; k0 < 1024; k0 += 64){
    #pragma unroll
    for (int j = 0; j < 4; ++j){
      const int cA = w*4 + j;
      const int r = cA*8 + rA;
      GL2LDS(Ag + (size_t)r*1024 + k0 + ce, As + cA*512);
      GL2LDS(Bg + (size_t)r*1024 + k0 + ce, Bs + cA*512);
    }
    __syncthreads();
    #pragma unroll
    for (int kk = 0; kk < 64; kk += 32){
      const int ch = ((quad + (kk >> 3)) ^ xr) * 8;
      v8s a[4], b[4];
      #pragma unroll
      for (int u = 0; u < 4; ++u) a[u] = *(v8s*)&As[(wm + u*16 + l16)*64 + ch];
      #pragma unroll
      for (int u = 0; u < 4; ++u) b[u] = *(v8s*)&Bs[(wn + u*16 + l16)*64 + ch];
      #pragma unroll
      for (int mi = 0; mi < 4; ++mi)
        #pragma unroll
        for (int ni = 0; ni < 4; ++ni)
          acc[mi][ni] = MFMA(a[mi], b[ni], acc[mi][ni]);
    }
    __syncthreads();
  }
  #pragma unroll
  for (int mi = 0; mi < 4; ++mi){
    const int m0 = bm*128 + wm + mi*16 + quad*4;
    const int b = m0 >> 11, t0 = m0 & 2047, cc = t0 >> 6, s0 = t0 & 63;
    #pragma unroll
    for (int ni = 0; ni < 4; ++ni){
      int n = bn*128 + wn + ni*16 + l16;
      int which = n >> 10, cch = n & 1023;
      int hh = cch >> 6, dd = cch & 63;
      const int bh = b*16 + hh;
      if (which == 0){
        #pragma unroll
        for (int r = 0; r < 4; ++r)
          qkv[(size_t)(bh*2048 + t0 + r)*64 + dd] = f2bf(acc[mi][ni][r]);
      } else {
        ushort4 o; o.x = f2bf(acc[mi][ni][0]); o.y = f2bf(acc[mi][ni][1]);
        o.z = f2bf(acc[mi][ni][2]); o.w = f2bf(acc[mi][ni][3]);
        const size_t tb = ((size_t)bh*32 + cc)*4096 + dd*64 + s0;
        if (which == 1){
          *(ushort4*)&KTg[tb] = o;
          #pragma unroll
          for (int r = 0; r < 4; ++r)
            qkv[SZ_BHTD + (size_t)(bh*2048 + t0 + r)*64 + dd] = f2bf(acc[mi][ni][r]);
        } else {
          *(ushort4*)&qkv[2*(size_t)SZ_BHTD + tb] = o;   // V^T
        }
      }
    }
  }
}

// Per (b,h,chunk): UT[d][e]=sum_s g^{63-s}V[s][d]K[s][e]; CK[d][e]=sum_s K[s][d]V[s][e];
// head[e] = qbar . pkv, qbar[d]=sum_j g^j Q[j][d]. No LDS staging: direct v8s fragment loads.
__global__ __launch_bounds__(256) void k_pre(const uint16_t* __restrict__ qkv, const uint16_t* __restrict__ KTg,
                                             const float* __restrict__ pkv,
                                             uint16_t* __restrict__ UT, uint16_t* __restrict__ ckp,
                                             float* __restrict__ headv){
  __shared__ float tab[65];
  __shared__ float qp[4][64];
  __shared__ float qbar[64];
  __shared__ float hp[4][64];
  const int tid = threadIdx.x, blk = blockIdx.x;
  const int bh = blk >> 5, c = blk & 31, h = bh & 15;
  const int lane = tid & 63, w = tid >> 6;
  const int quad = lane >> 4, l16 = lane & 15;
  const float g = 1.0f - exp2f(-(float)(5 + h));
  if (tid <= 64) tab[tid] = powf(g, (float)tid);
  __syncthreads();
  const uint16_t* Qg = qkv + (size_t)bh*SZ_HTD + c*4096;
  const uint16_t* KT = KTg + (size_t)blk*4096;
  const uint16_t* VT = qkv + 2*(size_t)SZ_BHTD + (size_t)blk*4096;
  const float* Pg = pkv + h*4096;
  const int row = w*16 + l16;
  v8s aK0 = *(const v8s*)&KT[row*64 + quad*8];
  v8s aK1 = *(const v8s*)&KT[row*64 + 32 + quad*8];
  v8s vt0 = *(const v8s*)&VT[row*64 + quad*8];
  v8s vt1 = *(const v8s*)&VT[row*64 + 32 + quad*8];
  v8s aW0, aW1;
  #pragma unroll
  for (int u = 0; u < 8; ++u){
    aW0[u] = (short)f2bf(tab[63 - (quad*8 + u)]*bf2f((uint16_t)vt0[u]));
    aW1[u] = (short)f2bf(tab[31 - (quad*8 + u)]*bf2f((uint16_t)vt1[u]));   // 63-(32+q8u)
  }
  v4f accC[4] = {}, accU[4] = {};
  #pragma unroll
  for (int ni = 0; ni < 4; ++ni){
    const int br = (ni*16 + l16)*64 + quad*8;
    v8s bV0 = *(const v8s*)&VT[br], bV1 = *(const v8s*)&VT[br + 32];
    v8s bK0 = *(const v8s*)&KT[br], bK1 = *(const v8s*)&KT[br + 32];
    accC[ni] = MFMA(aK0, bV0, accC[ni]);
    accC[ni] = MFMA(aK1, bV1, accC[ni]);
    accU[ni] = MFMA(aW0, bK0, accU[ni]);
    accU[ni] = MFMA(aW1, bK1, accU[ni]);
  }
  const size_t ob = (size_t)blk*4096;
  #pragma unroll
  for (int ni = 0; ni < 4; ++ni){
    int e = ni*16 + l16;
    #pragma unroll
    for (int r = 0; r < 4; ++r){
      int d = w*16 + quad*4 + r;
      ckp[ob + d*64 + e] = f2bf(accC[ni][r]);
      UT[ob + d*64 + e]  = f2bf(accU[ni][r]);
    }
  }
  // qbar / head with all 256 threads
  {
    int d = tid & 63, jg = tid >> 6;
    float a = 0.f;
    #pragma unroll
    for (int jj = 0; jj < 16; ++jj)
      a = fmaf(tab[jg*16 + jj], bf2f(Qg[(jg*16 + jj)*64 + d]), a);
    qp[jg][d] = a;
  }
  __syncthreads();
  if (tid < 64) qbar[tid] = qp[0][tid] + qp[1][tid] + qp[2][tid] + qp[3][tid];
  __syncthreads();
  {
    int e = tid & 63, dg = tid >> 6;
    float a = 0.f;
    #pragma unroll
    for (int dd = 0; dd < 16; ++dd)
      a = fmaf(qbar[dg*16 + dd], Pg[(dg*16 + dd)*64 + e], a);
    hp[dg][e] = a;
  }
  __syncthreads();
  if (tid < 64) headv[(size_t)blk*64 + tid] = hp[0][tid] + hp[1][tid] + hp[2][tid] + hp[3][tid];
}

// Merged scans. [0,256): forward state scan; [256,272): backward tail scan.
__global__ __launch_bounds__(256) void k_scan(const uint16_t* __restrict__ UT, uint16_t* __restrict__ S,
                                              const float* __restrict__ headv, float* __restrict__ tailv){
  if (blockIdx.x < 256){
    const int bh = blockIdx.x >> 2, part = blockIdx.x & 3, h = bh & 15;
    const float g = 1.0f - exp2f(-(float)(5 + h));
    const float g64 = powf(g, 64.0f);
    const int off = part*1024 + threadIdx.x*4;
    float st0=0.f, st1=0.f, st2=0.f, st3=0.f;
    for (int c = 0; c < 32; ++c){
      const size_t base = ((size_t)bh*32 + c)*4096 + off;
      ushort4 u = *(const ushort4*)&UT[base];
      ushort4 o; o.x=f2bf(st0); o.y=f2bf(st1); o.z=f2bf(st2); o.w=f2bf(st3);
      *(ushort4*)&S[base] = o;
      st0 = fmaf(g64, st0, bf2f(u.x)); st1 = fmaf(g64, st1, bf2f(u.y));
      st2 = fmaf(g64, st2, bf2f(u.z)); st3 = fmaf(g64, st3, bf2f(u.w));
    }
    return;
  }
  const int lin = (blockIdx.x - 256)*256 + threadIdx.x;   // 4096 = B*H*DH
  const int bh = lin >> 6, e = lin & 63, h = bh & 15;
  const float g = 1.0f - exp2f(-(float)(5 + h));
  const float g64 = powf(g, 64.0f);
  float R = 0.0f;
  for (int c = 31; c >= 0; --c){
    const size_t o = ((size_t)bh*32 + c)*64 + e;
    tailv[o] = R;
    R = fmaf(g64, R, headv[o]);
  }
}

// Fused main: stage-1 P=QK^T, pp=Q pkv^T, inter=Q S^T (direct global fragments);
// LDS round-trips for P', ppT; stage-2 intra=P'V, cx=M ppT; epilogue + stats partials.
__global__ __launch_bounds__(256) void k_main(const uint16_t* __restrict__ qkv, const uint16_t* __restrict__ Sg_,
                                              const uint16_t* __restrict__ pkvT, const float* __restrict__ tailv,
                                              uint16_t* __restrict__ ret, float2* __restrict__ pb){
  __shared__ uint16_t Pl[64*72];    // P' rows [i][s]
  __shared__ uint16_t Tp[64*72];    // ppT [e][j]
  __shared__ float tab[65];
  __shared__ float ps[8];
  const int tid = threadIdx.x, blk = blockIdx.x;
  const int bh = blk >> 5, c = blk & 31, h = bh & 15;
  const int lane = tid & 63, w = tid >> 6;
  const int quad = lane >> 4, l16 = lane & 15;
  const float g = 1.0f - exp2f(-(float)(5 + h));
  if (tid <= 64) tab[tid] = powf(g, (float)tid);
  const uint16_t* Qg = qkv + (size_t)bh*SZ_HTD + c*4096;
  const uint16_t* Kg = Qg + SZ_BHTD;
  const uint16_t* VT = qkv + 2*(size_t)SZ_BHTD + (size_t)blk*4096;
  const uint16_t* Sgp = Sg_ + (size_t)blk*4096;
  const uint16_t* PT = pkvT + h*4096;
  const int row = w*16 + l16;
  v8s aQ0 = *(const v8s*)&Qg[row*64 + quad*8];
  v8s aQ1 = *(const v8s*)&Qg[row*64 + 32 + quad*8];
  v4f accP[4] = {}, accPP[4] = {}, accIT[4] = {};
  #pragma unroll
  for (int ni = 0; ni < 4; ++ni){
    const int br = (ni*16 + l16)*64 + quad*8;
    v8s b0 = *(const v8s*)&Kg[br], b1 = *(const v8s*)&Kg[br + 32];
    accP[ni] = MFMA(aQ0, b0, accP[ni]);
    accP[ni] = MFMA(aQ1, b1, accP[ni]);
    v8s c0 = *(const v8s*)&PT[br], c1 = *(const v8s*)&PT[br + 32];
    accPP[ni] = MFMA(aQ0, c0, accPP[ni]);
    accPP[ni] = MFMA(aQ1, c1, accPP[ni]);
    v8s d0 = *(const v8s*)&Sgp[br], d1 = *(const v8s*)&Sgp[br + 32];
    accIT[ni] = MFMA(aQ0, d0, accIT[ni]);
    accIT[ni] = MFMA(aQ1, d1, accIT[ni]);
  }
  __syncthreads();                  // tab ready
  #pragma unroll
  for (int ni = 0; ni < 4; ++ni){
    #pragma unroll
    for (int r = 0; r < 4; ++r){
      int i = w*16 + quad*4 + r;
      int j = ni*16 + l16;
      Pl[i*72 + j] = f2bf((i >= j) ? accP[ni][r]*tab[i - j] : 0.0f);
      Tp[j*72 + i] = f2bf(accPP[ni][r]);
    }
  }
  __syncthreads();
  v8s aP0 = *(v8s*)&Pl[row*72 + quad*8], aP1 = *(v8s*)&Pl[row*72 + 32 + quad*8];
  v8s aM0, aM1;
  {
    int i = row;
    #pragma unroll
    for (int u = 0; u < 8; ++u){
      int j0 = quad*8 + u, j1 = 32 + quad*8 + u;
      aM0[u] = (short)f2bf((j0 >= i) ? tab[j0 - i] : 0.0f);
      aM1[u] = (short)f2bf((j1 >= i) ? tab[j1 - i] : 0.0f);
    }
  }
  v4f accI[4] = {}, accX[4] = {};
  #pragma unroll
  for (int ni = 0; ni < 4; ++ni){
    const int bg = (ni*16 + l16)*64 + quad*8;
    v8s b0 = *(const v8s*)&VT[bg], b1 = *(const v8s*)&VT[bg + 32];
    accI[ni] = MFMA(aP0, b0, accI[ni]);
    accI[ni] = MFMA(aP1, b1, accI[ni]);
    const int bl = (ni*16 + l16)*72 + quad*8;
    v8s e0 = *(v8s*)&Tp[bl], e1 = *(v8s*)&Tp[bl + 32];
    accX[ni] = MFMA(aM0, e0, accX[ni]);
    accX[ni] = MFMA(aM1, e1, accX[ni]);
  }
  const size_t rbase = (size_t)bh*2048 + (size_t)c*64;
  float s1 = 0.f, s2 = 0.f;
  #pragma unroll
  for (int ni = 0; ni < 4; ++ni){
    int d = ni*16 + l16;
    float tl = tailv[(size_t)blk*64 + d];
    #pragma unroll
    for (int r = 0; r < 4; ++r){
      int i = w*16 + quad*4 + r;
      float v = accI[ni][r] + tab[i + 1]*accIT[ni][r] + accX[ni][r] + tab[64 - i]*tl;
      ret[(rbase + i)*64 + d] = f2bf(v);
      s1 += v; s2 += v*v;
    }
  }
  #pragma unroll
  for (int off = 32; off > 0; off >>= 1){
    s1 += __shfl_down(s1, off);
    s2 += __shfl_down(s2, off);
  }
  if (lane == 0){ ps[w*2] = s1; ps[w*2+1] = s2; }
  __syncthreads();
  if (tid == 0){
    float2 o; o.x = ps[0] + ps[2] + ps[4] + ps[6];
    o.y = ps[1] + ps[3] + ps[5] + ps[7];
    pb[blk] = o;
  }
}

// reduce 512 per-block partials per batch -> stats
__global__ __launch_bounds__(256) void k_stats(const float2* __restrict__ pb, float* __restrict__ stats){
  __shared__ float ps[8];
  const int b = blockIdx.x;
  float s = 0.0f, s2 = 0.0f;
  for (int i = threadIdx.x; i < 512; i += 256){
    const float2 p = pb[(size_t)b*512 + i];
    s += p.x; s2 += p.y;
  }
  #pragma unroll
  for (int off = 32; off > 0; off >>= 1){
    s  += __shfl_down(s, off);
    s2 += __shfl_down(s2, off);
  }
  const int wv = threadIdx.x >> 6;
  if ((threadIdx.x & 63) == 0){ ps[wv*2] = s; ps[wv*2+1] = s2; }
  __syncthreads();
  if (threadIdx.x == 0){
    stats[b*2]   = ps[0] + ps[2] + ps[4] + ps[6];
    stats[b*2+1] = ps[1] + ps[3] + ps[5] + ps[7];
  }
}

// GroupNorm apply + layout to [B,T,NE]
__global__ __launch_bounds__(256) void k_norm(const uint16_t* __restrict__ ret, const float* __restrict__ stats,
                                              const float* __restrict__ gw, const float* __restrict__ gb,
                                              float* __restrict__ out){
  const int o = (blockIdx.x*256 + threadIdx.x)*4;
  const int b = o >> 21, t = (o >> 10) & 2047, cch = o & 1023;
  const int h = cch >> 6, d = cch & 63;
  const float inv = 1.0f/2097152.0f;
  const float mu = stats[b*2]*inv;
  const float var = stats[b*2+1]*inv - mu*mu;
  const float rs = rsqrtf(var + 1e-5f);
  const float w = gw[h]*rs, bb = gb[h];
  const ushort4 v = *(const ushort4*)&ret[((size_t)(b*16 + h)*2048 + t)*64 + d];
  float4 r;
  r.x = (bf2f(v.x) - mu)*w + bb; r.y = (bf2f(v.y) - mu)*w + bb;
  r.z = (bf2f(v.z) - mu)*w + bb; r.w = (bf2f(v.w) - mu)*w + bb;
  *(float4*)&out[o] = r;
}

// current_kv = gamma*past_kv + mean_b K^T V   (256 blocks: (h, de-part))
__global__ __launch_bounds__(256) void k_ckb(const float* __restrict__ pkv, const uint16_t* __restrict__ ckp,
                                             float* __restrict__ out2){
  const int h = blockIdx.x >> 4, part = blockIdx.x & 15;
  const int de = part*256 + threadIdx.x;
  const float g = 1.0f - exp2f(-(float)(5 + h));
  float acc = 0.0f;
  #pragma unroll 4
  for (int b = 0; b < 4; ++b){
    const uint16_t* base = ckp + ((size_t)(b*16 + h)*32)*4096 + de;
    for (int c = 0; c < 32; ++c) acc += bf2f(base[(size_t)c*4096]);
  }
  const int i = h*4096 + de;
  out2[i] = fmaf(g, pkv[i], 0.25f*acc);
}

extern "C" void kernel_launch(void* const* d_in, const int* in_sizes, int n_in,
                              void* d_out, int out_size, void* d_ws, size_t ws_size,
                              hipStream_t stream){
  const float* x   = (const float*)d_in[0];
  const float* pkv = (const float*)d_in[1];
  const float* Wq  = (const float*)d_in[2];
  const float* Wk  = (const float*)d_in[3];
  const float* Wv  = (const float*)d_in[4];
  const float* gnw = (const float*)d_in[5];
  const float* gnb = (const float*)d_in[6];
  float* out  = (float*)d_out;
  float* out2 = out + 8388608;

  char* ws = (char*)d_ws;
  size_t off = 0;
  float*    stats = (float*)(ws + off);    off += 256;
  float2*   pb    = (float2*)(ws + off);   off += (size_t)8192*8;
  uint16_t* Xb    = (uint16_t*)(ws + off); off += (size_t)8388608*2;
  uint16_t* Wt    = (uint16_t*)(ws + off); off += (size_t)3145728*2;
  uint16_t* QKV   = (uint16_t*)(ws + off); off += (size_t)3*8388608*2;   // Q, K, V^T
  uint16_t* KTg   = (uint16_t*)(ws + off); off += (size_t)8388608*2;
  uint16_t* ret   = (uint16_t*)(ws + off); off += (size_t)8388608*2;
  uint16_t* UT    = (uint16_t*)(ws + off); off += (size_t)8388608*2;
  uint16_t* S     = (uint16_t*)(ws + off); off += (size_t)8388608*2;
  uint16_t* CKp   = (uint16_t*)(ws + off); off += (size_t)8388608*2;
  uint16_t* pkvT  = (uint16_t*)(ws + off); off += (size_t)65536*2;
  float*    headv = (float*)(ws + off);    off += (size_t)131072*4;
  float*    tailv = (float*)(ws + off);    off += (size_t)131072*4;

  k_conv<<<8976, 256, 0, stream>>>(x, Wq, Wk, Wv, pkv, Xb, Wt, pkvT);
  k_gemm<<<dim3(64, 24), 256, 0, stream>>>(Xb, Wt, QKV, KTg);
  k_pre<<<2048, 256, 0, stream>>>(QKV, KTg, pkv, UT, CKp, headv);
  k_scan<<<272, 256, 0, stream>>>(UT, S, headv, tailv);
  k_main<<<2048, 256, 0, stream>>>(QKV, S, pkvT, tailv, ret, pb);
  k_stats<<<4, 256, 0, stream>>>(pb, stats);
  k_norm<<<8192, 256, 0, stream>>>(ret, stats, gnw, gnb, out);
  k_ckb<<<256, 256, 0, stream>>>(pkv, CKp, out2);
}